// Round 14
// baseline (79.314 us; speedup 1.0000x reference)
//
#include <hip/hip_runtime.h>
#include <stdint.h>

// Problem: B,T,C = 2,768,64; N_HEAD=64 -> head_dim=1; fp32 buffers.
// Unified model (R11 probe + R12/R13 flat results): inner iter ~38 cyc of
// which 2x v_exp_f32 ~= 32 cyc (trans pipe, ~16 cyc/wave64). The exp is the
// wall; k/v transport pipe (DS/SMEM/VMEM) never was. R14: hybrid exp —
// e.x on trans pipe, e.y on VALU via 7-op cubic poly + exponent-field add
// (sc in [-30,2.3] after skip -> no denorm/overflow). Pipes overlap across
// waves => per-iter cost max(16 trans, ~22 VALU) vs 38.
constexpr int Tc = 768;
constexpr int Hc = 64;
constexpr int Bc = 2;
constexpr float LOG2E = 1.44269504088896f;
constexpr size_t SLAB = (size_t)Bc * Hc * Tc;   // 98304 floats per slab

typedef float v2f __attribute__((ext_vector_type(2)));
typedef float v4f __attribute__((ext_vector_type(4)));

// ---------------------------------------------------------------------------
// Kernel 1: projection into transposed slabs (measured ~3 us, R7).
// ---------------------------------------------------------------------------
__global__ __launch_bounds__(256) void proj_kernel(
    const float* __restrict__ x, const float* __restrict__ W,
    const float* __restrict__ vtmp, const float* __restrict__ ptmp,
    float* __restrict__ qs, float* __restrict__ ks, float* __restrict__ vs)
{
    const int lane = threadIdx.x & 63;
    const int w    = __builtin_amdgcn_readfirstlane(threadIdx.x >> 6);
    const int g    = blockIdx.x * 64 + lane;     // global row in [0,1536)
    const int bh0  = (g / Tc) * Hc;              // b*64 (64 | 768: no straddle)
    const int t    = g % Tc;
    const int h    = blockIdx.y * 4 + w;         // wave-uniform head

    float xr[64];
    const v4f* xp = (const v4f*)(x + (size_t)g * 64);
#pragma unroll
    for (int c = 0; c < 16; ++c) ((v4f*)xr)[c] = xp[c];

    const float* __restrict__ wq = W + h * 64;
    const float* __restrict__ wk = W + (64 + h) * 64;
    float aq = 0.f, ak = 0.f;
#pragma unroll
    for (int c = 0; c < 64; ++c) {               // constant indices only
        aq = fmaf(xr[c], wq[c], aq);
        ak = fmaf(xr[c], wk[c], ak);
    }
    const size_t o = (size_t)(bh0 + h) * Tc + t;   // lane-coalesced
    qs[o] = aq * LOG2E;
    ks[o] = ak;
    vs[o] = x[(size_t)g * 64 + h] * vtmp[h] * ptmp[h];   // global reload, not xr[h]
}

// VALU-pipe exp2: rndne + sub + 3 fma + cvt + exponent-field add (~7 ops).
// Valid for x in [-120, 120], rel err <= ~6e-4 (Taylor cubic on [-0.5,0.5]).
__device__ __forceinline__ float fast_exp2(float x) {
    float n = __builtin_rintf(x);                    // v_rndne_f32
    float r = x - n;                                 // r in [-0.5, 0.5]
    float p = fmaf(r, fmaf(r, fmaf(r, 0.05550411f, 0.24022651f),
                           0.69314718f), 1.0f);      // 2^r
    return __int_as_float(__float_as_int(p) + ((int)n << 23));  // * 2^n exact
}

// ---------------------------------------------------------------------------
// Kernel 2: attention. Block = (rt: 64 rows, h, b); lane = row; 4 waves = 4
// j-quarters (192 j). Per 16-j chunk: k[16], v[16] from ws (L2-resident);
// 8 packed iters; HYBRID exp: e.x trans pipe, e.y VALU poly. Wave-uniform
// chunk classes: [skip] | past (no min) | mixed (full) | future (bias=0).
// grid (12,64,2) = 1536 = 6 blocks/CU, 24 waves/CU.
// ---------------------------------------------------------------------------
__global__ __launch_bounds__(256, 6) void attn_kernel(
    const float* __restrict__ qs, const float* __restrict__ ks,
    const float* __restrict__ vs, float* __restrict__ out)
{
    const int tid  = threadIdx.x;
    const int lane = tid & 63;
    const int w    = __builtin_amdgcn_readfirstlane(tid >> 6);
    const int rt   = blockIdx.x;   // 0..11 (64-row tile)
    const int h    = blockIdx.y;
    const int b    = blockIdx.z;
    const int bh   = b * Hc + h;

    __shared__ float psum[4][64], pacc[4][64];   // 2 KB only

    const float* __restrict__ kp = ks + (size_t)bh * Tc;
    const float* __restrict__ vp = vs + (size_t)bh * Tc;

    const int i = rt * 64 + lane;            // this lane's query row
    const float q = qs[(size_t)bh * Tc + i]; // coalesced, log2e folded
    // slopes[h] = 2^(-(h+1)/8) (H=64), folded with log2(e)
    const float slope2 = exp2f(-0.125f * (float)(h + 1)) * LOG2E;

    v2f cu2[8];                              // {slope*(2u), slope*(2u+1)}
#pragma unroll
    for (int u = 0; u < 8; ++u) {
        cu2[u].x = slope2 * (float)(2 * u);
        cu2[u].y = slope2 * (float)(2 * u + 1);
    }

    const int j0 = w * (Tc / 4);             // this wave's 192-j quarter
    // ALiBi distant-past skip: chunks entirely below i_min - 28/slope2
    int c0 = 0;
    {
        const int jskip = rt * 64 - (int)(28.f / slope2);
        if (jskip > j0) {
            c0 = (jskip - j0) >> 4;
            if (c0 > 12) c0 = 12;
        }
    }

    v2f sum2 = {0.f, 0.f}, acc2 = {0.f, 0.f};
    const v2f q2 = {q, q};

    for (int c = c0; c < 12; ++c) {          // chunks of 16 j (8 packed iters)
        const int jc = j0 + 16 * c;          // wave-uniform
        float kk[16], vv[16];
        const float* __restrict__ kc = kp + jc;
        const float* __restrict__ vc = vp + jc;
#pragma unroll
        for (int u = 0; u < 16; ++u) { kk[u] = kc[u]; vv[u] = vc[u]; }

        const float mb = slope2 * (float)(jc - i);
        const v2f mb2 = {mb, mb};
        if (jc >= rt * 64 + 64) {
            // FUTURE: all j > all i -> bias = 0
#pragma unroll
            for (int u = 0; u < 8; ++u) {
                v2f k2 = {kk[2 * u], kk[2 * u + 1]};
                v2f v2 = {vv[2 * u], vv[2 * u + 1]};
                v2f sc = q2 * k2;            // v_pk_mul_f32
                v2f e;
                e.x = __builtin_amdgcn_exp2f(sc.x);   // trans pipe
                e.y = fast_exp2(sc.y);                // VALU pipe
                sum2 += e;
                acc2 = e * v2 + acc2;        // v_pk_fma_f32
            }
        } else if (jc + 15 < rt * 64) {
            // PAST: all j < all i -> bias = slope*(j-i) (no min)
#pragma unroll
            for (int u = 0; u < 8; ++u) {
                v2f k2 = {kk[2 * u], kk[2 * u + 1]};
                v2f v2 = {vv[2 * u], vv[2 * u + 1]};
                v2f bias = mb2 + cu2[u];
                v2f sc = q2 * k2 + bias;
                v2f e;
                e.x = __builtin_amdgcn_exp2f(sc.x);
                e.y = fast_exp2(sc.y);
                sum2 += e;
                acc2 = e * v2 + acc2;
            }
        } else {
            // MIXED (diagonal band): full path with min
#pragma unroll
            for (int u = 0; u < 8; ++u) {
                v2f k2 = {kk[2 * u], kk[2 * u + 1]};
                v2f v2 = {vv[2 * u], vv[2 * u + 1]};
                v2f t2 = mb2 + cu2[u];
                v2f bias;
                bias.x = fminf(t2.x, 0.f);
                bias.y = fminf(t2.y, 0.f);
                v2f sc = q2 * k2 + bias;
                v2f e;
                e.x = __builtin_amdgcn_exp2f(sc.x);
                e.y = fast_exp2(sc.y);
                sum2 += e;
                acc2 = e * v2 + acc2;
            }
        }
    }
    psum[w][lane] = sum2.x + sum2.y;
    pacc[w][lane] = acc2.x + acc2.y;
    __syncthreads();

    // ---- combine 4 j-quarters, write out ----
    if (tid < 64) {
        float s = psum[0][lane] + psum[1][lane] + psum[2][lane] + psum[3][lane];
        float a = pacc[0][lane] + pacc[1][lane] + pacc[2][lane] + pacc[3][lane];
        out[((size_t)(b * Tc + rt * 64 + lane)) * 64 + h] =
            a * __builtin_amdgcn_rcpf(s);
    }
}

extern "C" void kernel_launch(void* const* d_in, const int* in_sizes, int n_in,
                              void* d_out, int out_size, void* d_ws, size_t ws_size,
                              hipStream_t stream) {
    const float* x    = (const float*)d_in[0];
    const float* W    = (const float*)d_in[1];
    const float* vtmp = (const float*)d_in[2];
    const float* ptmp = (const float*)d_in[3];
    float* out = (float*)d_out;

    float* qsl = (float*)d_ws;
    float* ksl = qsl + SLAB;
    float* vsl = ksl + SLAB;

    proj_kernel<<<dim3(24, 16), 256, 0, stream>>>(x, W, vtmp, ptmp, qsl, ksl, vsl);
    attn_kernel<<<dim3(12, Hc, Bc), 256, 0, stream>>>(qsl, ksl, vsl, out);
}